// Round 1
// baseline (1573.183 us; speedup 1.0000x reference)
//
#include <hip/hip_runtime.h>

// ---------- types / helpers ----------
typedef short s16x8 __attribute__((ext_vector_type(8)));   // 8 bf16 (4 VGPRs) MFMA A/B frag
typedef float f32x4 __attribute__((ext_vector_type(4)));   // MFMA C/D frag
typedef unsigned short u16x4 __attribute__((ext_vector_type(4)));

#define MFMA_B16(a, b, c) __builtin_amdgcn_mfma_f32_16x16x32_bf16((a), (b), (c), 0, 0, 0)

__device__ __forceinline__ unsigned short f2b(float f) {   // fp32 -> bf16 RNE
    unsigned u = __builtin_bit_cast(unsigned, f);
    u = (u + 0x7fffu + ((u >> 16) & 1u)) >> 16;
    return (unsigned short)u;
}
__device__ __forceinline__ float b2f(unsigned short h) {
    unsigned u = ((unsigned)h) << 16;
    return __builtin_bit_cast(float, u);
}
__device__ __forceinline__ float sigm(float x) { return 1.f / (1.f + __expf(-x)); }
__device__ __forceinline__ float tanh_f(float x) {
    float t = __expf(-2.f * fabsf(x));
    float r = (1.f - t) / (1.f + t);
    return copysignf(r, x);
}

// ---------- device-coherent (sc1 / LLC) data ops ----------
__device__ __forceinline__ void stg_b16_sc(unsigned short* p, unsigned short v) {
    unsigned v32 = v;
    asm volatile("global_store_short %0, %1, off sc1" :: "v"(p), "v"(v32) : "memory");
}
__device__ __forceinline__ void stg_b32_sc(float* p, float v) {
    asm volatile("global_store_dword %0, %1, off sc1" :: "v"(p), "v"(v) : "memory");
}
__device__ __forceinline__ unsigned long long ldg_u64_sc(const void* p) {
    return __hip_atomic_load((unsigned long long*)p, __ATOMIC_RELAXED, __HIP_MEMORY_SCOPE_AGENT);
}
__device__ __forceinline__ float ldg_b16_sc(const unsigned short* p) {
    unsigned short v = __hip_atomic_load((unsigned short*)p, __ATOMIC_RELAXED, __HIP_MEMORY_SCOPE_AGENT);
    return b2f(v);
}
__device__ __forceinline__ float ldg_f32_sc(const float* p) {
    return __hip_atomic_load((float*)p, __ATOMIC_RELAXED, __HIP_MEMORY_SCOPE_AGENT);
}
__device__ __forceinline__ s16x8 ldA_sc(const unsigned short* p) {
    union { unsigned long long u[2]; s16x8 v; } r;
    r.u[0] = ldg_u64_sc(p);
    r.u[1] = ldg_u64_sc((const unsigned long long*)p + 1);
    return r.v;
}

// ---------- XCD-local (L2-coherent) flag load: bypass L1 only ----------
__device__ __forceinline__ int ld_flag_sc0(const int* p) {
    int v;
    asm volatile("global_load_dword %0, %1, off sc0\n\ts_waitcnt vmcnt(0)"
                 : "=v"(v) : "v"(p) : "memory");
    return v;
}

// ---------- flag protocol ----------
// remote flags: one 64B-separated dword per producer block (sc1 / LLC), as before.
// local flags:  dense 4B-stride dwords; producers plain-store (write-through to local L2),
//               consumers poll sc0. Sticky timeout -> fall back to the remote sc1 copy.
#define TMO 3000

__device__ __forceinline__ void block_publish(int* flag, int v) {  // remote publish
    asm volatile("s_waitcnt vmcnt(0)" ::: "memory");
    __syncthreads();
    if (threadIdx.x == 0)
        __hip_atomic_store(flag, v, __ATOMIC_RELAXED, __HIP_MEMORY_SCOPE_AGENT);
}
__device__ __forceinline__ void publish_l(int* fl, int v) {        // local publish
    asm volatile("s_waitcnt vmcnt(0)" ::: "memory");
    __syncthreads();
    if (threadIdx.x == 0) *(volatile int*)fl = v;
}
template <int SLP>
__device__ __forceinline__ void flags_wait2(const int* f1, int t1, const int* f2, int t2) {
    const int lane = threadIdx.x & 63;
    const int* ptr = (lane < 32) ? (f1 + lane * 16) : (f2 + (lane - 32) * 16);
    const int tgt = (lane < 32) ? t1 : t2;
    for (;;) {
        int v = __hip_atomic_load((int*)ptr, __ATOMIC_RELAXED, __HIP_MEMORY_SCOPE_AGENT);
        if (__all(v >= tgt)) break;
        __builtin_amdgcn_s_sleep(SLP);
    }
}
template <int SLP>
__device__ __forceinline__ void flags_wait(const int* f, int t) {
    flags_wait2<SLP>(f, t, f, t);
}
// local 32-flag wait with sticky sc1 fallback
template <int SLP>
__device__ __forceinline__ void wait32(const int* fl, const int* fr, int t, int& fb) {
    const int li = threadIdx.x & 31;
    int it = 0;
    for (;;) {
        int v;
        if (!fb) v = ld_flag_sc0(fl + li);
        else v = __hip_atomic_load((int*)(fr + li * 16), __ATOMIC_RELAXED, __HIP_MEMORY_SCOPE_AGENT);
        if (__all(v >= t)) return;
        if (!fb && ++it > TMO) fb = 1;
        __builtin_amdgcn_s_sleep(SLP);
    }
}
// combined: lanes 0..31 poll remote fr1 (sc1); lanes 32..63 poll local fl2 (sc0, fallback fr2)
template <int SLP>
__device__ __forceinline__ void wait_rl(const int* fr1, int t1, const int* fl2, const int* fr2,
                                        int t2, int& fb) {
    const int lane = threadIdx.x & 63;
    int it = 0;
    for (;;) {
        int v, tg;
        if (lane < 32) {
            v = __hip_atomic_load((int*)(fr1 + lane * 16), __ATOMIC_RELAXED, __HIP_MEMORY_SCOPE_AGENT);
            tg = t1;
        } else {
            const int li = lane - 32;
            if (!fb) v = ld_flag_sc0(fl2 + li);
            else v = __hip_atomic_load((int*)(fr2 + li * 16), __ATOMIC_RELAXED, __HIP_MEMORY_SCOPE_AGENT);
            tg = t2;
        }
        if (__all(v >= tg)) return;
        if (!fb && ++it > TMO) fb = 1;
        __builtin_amdgcn_s_sleep(SLP);
    }
}
template <int SLP>
__device__ __forceinline__ void scalar_wait(int* c, int target) {
    while (__hip_atomic_load(c, __ATOMIC_RELAXED, __HIP_MEMORY_SCOPE_AGENT) < target)
        __builtin_amdgcn_s_sleep(SLP);
}
__device__ __forceinline__ void wave_add(int* c) {   // per-wave count (after drain)
    asm volatile("s_waitcnt vmcnt(0)" ::: "memory");
    if ((threadIdx.x & 63) == 0)
        __hip_atomic_fetch_add(c, 1, __ATOMIC_RELAXED, __HIP_MEMORY_SCOPE_AGENT);
}

// ---------- swizzled LDS weight tiles (16x512 bf16 in B-fragment order; conflict-free) ----------
#define WTILE 8192  // shorts per tile
#define WF(Wl, t, c, lane) (*(const s16x8*)((Wl) + (((t) * 16 + (c)) * 64 + (lane)) * 8))

__device__ __forceinline__ void stage_swz(const unsigned short* __restrict__ src,
                                          unsigned short* dst) {
    for (int idx = threadIdx.x; idx < 1024; idx += 256) {
        const int ln = idx & 63;
        *(uint4*)(dst + (size_t)idx * 8) =
            *(const uint4*)(src + (size_t)(ln & 15) * 512 + (ln >> 4) * 8 + ((idx >> 6)) * 32);
    }
}

// ---------- micro-GEMMs ----------
// sc1 (LLC) A operand
__device__ __forceinline__ void mm3_s(const unsigned short* __restrict__ A, int m0,
                                      const unsigned short* Wl, int lane,
                                      f32x4& a0, f32x4& a1, f32x4& a2) {
    const unsigned short* ab = A + (size_t)(m0 + (lane & 15)) * 512 + (lane >> 4) * 8;
#pragma unroll
    for (int c = 0; c < 16; ++c) {
        s16x8 a = ldA_sc(ab + c * 32);
        a0 = MFMA_B16(a, WF(Wl, 0, c, lane), a0);
        a1 = MFMA_B16(a, WF(Wl, 1, c, lane), a1);
        a2 = MFMA_B16(a, WF(Wl, 2, c, lane), a2);
    }
}
// plain (XCD-local, write-once buffer) A operand
__device__ __forceinline__ void mm3_p(const unsigned short* __restrict__ A, int m0,
                                      const unsigned short* Wl, int lane,
                                      f32x4& a0, f32x4& a1, f32x4& a2) {
    const unsigned short* ab = A + (size_t)(m0 + (lane & 15)) * 512 + (lane >> 4) * 8;
#pragma unroll
    for (int c = 0; c < 16; ++c) {
        s16x8 a = *(const s16x8*)(ab + c * 32);
        a0 = MFMA_B16(a, WF(Wl, 0, c, lane), a0);
        a1 = MFMA_B16(a, WF(Wl, 1, c, lane), a1);
        a2 = MFMA_B16(a, WF(Wl, 2, c, lane), a2);
    }
}
__device__ __forceinline__ void mm6_s(const unsigned short* __restrict__ A0,
                                      const unsigned short* __restrict__ A1, int m0,
                                      const unsigned short* Wl, int lane,
                                      f32x4& aR, f32x4& aZ, f32x4& aIN, f32x4& aHN) {
    const unsigned short* a0 = A0 + (size_t)(m0 + (lane & 15)) * 512 + (lane >> 4) * 8;
    const unsigned short* a1 = A1 + (size_t)(m0 + (lane & 15)) * 512 + (lane >> 4) * 8;
#pragma unroll
    for (int c = 0; c < 16; ++c) {
        s16x8 x0 = ldA_sc(a0 + c * 32);
        s16x8 x1 = ldA_sc(a1 + c * 32);
        aR  = MFMA_B16(x0, WF(Wl, 0, c, lane), aR);
        aZ  = MFMA_B16(x0, WF(Wl, 1, c, lane), aZ);
        aIN = MFMA_B16(x0, WF(Wl, 2, c, lane), aIN);
        aR  = MFMA_B16(x1, WF(Wl, 3, c, lane), aR);
        aZ  = MFMA_B16(x1, WF(Wl, 4, c, lane), aZ);
        aHN = MFMA_B16(x1, WF(Wl, 5, c, lane), aHN);
    }
}
// A0 remote (sc1), A1 local plain
__device__ __forceinline__ void mm6_rp(const unsigned short* __restrict__ A0,
                                       const unsigned short* __restrict__ A1, int m0,
                                       const unsigned short* Wl, int lane,
                                       f32x4& aR, f32x4& aZ, f32x4& aIN, f32x4& aHN) {
    const unsigned short* a0 = A0 + (size_t)(m0 + (lane & 15)) * 512 + (lane >> 4) * 8;
    const unsigned short* a1 = A1 + (size_t)(m0 + (lane & 15)) * 512 + (lane >> 4) * 8;
#pragma unroll
    for (int c = 0; c < 16; ++c) {
        s16x8 x0 = ldA_sc(a0 + c * 32);
        s16x8 x1 = *(const s16x8*)(a1 + c * 32);
        aR  = MFMA_B16(x0, WF(Wl, 0, c, lane), aR);
        aZ  = MFMA_B16(x0, WF(Wl, 1, c, lane), aZ);
        aIN = MFMA_B16(x0, WF(Wl, 2, c, lane), aIN);
        aR  = MFMA_B16(x1, WF(Wl, 3, c, lane), aR);
        aZ  = MFMA_B16(x1, WF(Wl, 4, c, lane), aZ);
        aHN = MFMA_B16(x1, WF(Wl, 5, c, lane), aHN);
    }
}

// ---------- prep ----------
__global__ void prep_kernel(const float* __restrict__ x, const float* __restrict__ Wih_v,
                            const float* __restrict__ Whh_v, const float* __restrict__ Whh_c,
                            const float* __restrict__ Wih_c, const float* __restrict__ Wout,
                            unsigned short* __restrict__ xB, unsigned short* __restrict__ WihB,
                            unsigned short* __restrict__ WhhvB, unsigned short* __restrict__ WhhcB,
                            unsigned short* __restrict__ WchhB, unsigned short* __restrict__ WoutB,
                            unsigned short* __restrict__ zeroB, int* __restrict__ ctrs,
                            float* __restrict__ out) {
    const int n = gridDim.x * blockDim.x;
    const int id0 = blockIdx.x * blockDim.x + threadIdx.x;
    for (int i = id0; i < 5242880; i += n) {   // x (b,t,f) fp32 -> xB (t*64+b, f) bf16
        const int e = i * 4;
        const int f = e & 4095, bt = e >> 12;  // bt = b*80+t
        const int b = bt / 80, t = bt - b * 80;
        float4 v = *(const float4*)(x + (size_t)e);
        u16x4 s = {f2b(v.x), f2b(v.y), f2b(v.z), f2b(v.w)};
        *(u16x4*)(xB + (size_t)(t * 64 + b) * 4096 + f) = s;
    }
    for (int i = id0; i < 1572864; i += n) {
        float4 v = *(const float4*)(Wih_v + (size_t)i * 4);
        u16x4 s = {f2b(v.x), f2b(v.y), f2b(v.z), f2b(v.w)};
        *(u16x4*)(WihB + (size_t)i * 4) = s;
    }
    for (int i = id0; i < 196608; i += n) {    // Whh_v / Whh_c / Wih_c[:, :512], vectorized
        const int e = i * 4;
        float4 a = *(const float4*)(Whh_v + e);
        u16x4 sa = {f2b(a.x), f2b(a.y), f2b(a.z), f2b(a.w)};
        *(u16x4*)(WhhvB + e) = sa;
        float4 b = *(const float4*)(Whh_c + e);
        u16x4 sb = {f2b(b.x), f2b(b.y), f2b(b.z), f2b(b.w)};
        *(u16x4*)(WhhcB + e) = sb;
        float4 d = *(const float4*)(Wih_c + (size_t)(e >> 9) * 6512 + (e & 511));
        u16x4 sd = {f2b(d.x), f2b(d.y), f2b(d.z), f2b(d.w)};
        *(u16x4*)(WchhB + e) = sd;
    }
    for (int i = id0; i < 768000; i += n) {    // Wout, vectorized
        float4 a = *(const float4*)(Wout + (size_t)i * 4);
        u16x4 s = {f2b(a.x), f2b(a.y), f2b(a.z), f2b(a.w)};
        *(u16x4*)(WoutB + (size_t)i * 4) = s;
    }
    for (int i = id0; i < 384000; i += n)      // probs[:,0,:] = 0 except probs[0,0,1]=1
        out[(size_t)(i / 6000) * 192000 + (i % 6000)] = (i == 1) ? 1.f : 0.f;
    for (int i = id0; i < 8192; i += n) ((unsigned long long*)zeroB)[i] = 0ull;
    for (int i = id0; i < 4096; i += n) ctrs[i] = 0;
}

// ---------- GEMM1 (bf16 in): gi[t*64+b, g] = xB[t*64+b,:] . WihB[g,:] + bih[g] ----------
__global__ __launch_bounds__(256) void gemm1_kernel(const unsigned short* __restrict__ xB,
                                                    const unsigned short* __restrict__ WihB,
                                                    const float* __restrict__ bih,
                                                    float* __restrict__ gi) {
    __shared__ unsigned short As[128 * 40];
    __shared__ unsigned short Bs[128 * 40];
    const int bm = blockIdx.x % 40;
    const int bn = blockIdx.x / 40;
    const int m0 = bm * 128, n0 = bn * 128;
    const int tid = threadIdx.x;
    const int lane = tid & 63;
    const int wave = tid >> 6;
    const int wm = (wave >> 1) * 64, wn = (wave & 1) * 64;
    const int quad = lane >> 4, l15 = lane & 15;

    const f32x4 z4 = {0.f, 0.f, 0.f, 0.f};
    f32x4 acc[4][4];
#pragma unroll
    for (int i = 0; i < 4; ++i)
#pragma unroll
        for (int j = 0; j < 4; ++j) acc[i][j] = z4;

    const int sr = tid >> 1;
    const int sc0 = (tid & 1) * 16;

    for (int k0 = 0; k0 < 4096; k0 += 32) {
        __syncthreads();
#pragma unroll
        for (int p = 0; p < 2; ++p) {
            const int c8 = sc0 + p * 8;
            *(s16x8*)&As[sr * 40 + c8] =
                *(const s16x8*)(xB + (size_t)(m0 + sr) * 4096 + k0 + c8);
            *(s16x8*)&Bs[sr * 40 + c8] =
                *(const s16x8*)(WihB + (size_t)(n0 + sr) * 4096 + k0 + c8);
        }
        __syncthreads();
        s16x8 af[4], bfr[4];
#pragma unroll
        for (int i = 0; i < 4; ++i) af[i] = *(const s16x8*)&As[(wm + i * 16 + l15) * 40 + quad * 8];
#pragma unroll
        for (int j = 0; j < 4; ++j) bfr[j] = *(const s16x8*)&Bs[(wn + j * 16 + l15) * 40 + quad * 8];
#pragma unroll
        for (int i = 0; i < 4; ++i)
#pragma unroll
            for (int j = 0; j < 4; ++j) acc[i][j] = MFMA_B16(af[i], bfr[j], acc[i][j]);
    }
#pragma unroll
    for (int i = 0; i < 4; ++i)
#pragma unroll
        for (int j = 0; j < 4; ++j)
#pragma unroll
            for (int r = 0; r < 4; ++r) {
                const int m = m0 + wm + i * 16 + quad * 4 + r;
                const int nn = n0 + wn + j * 16 + l15;
                gi[(size_t)m * 1536 + nn] = acc[i][j][r] + bih[nn];
            }
}

// ---------- persistent pipeline kernel ----------
// LOCAL mode (256 blocks, 1/CU => exactly 32 blocks per XCD):
//   XCD0 -> group_v (spine: enc_v + decoder h_v2 + loss), all chain traffic via XCD0 L2
//   XCD1 -> group_c (enc_c + decoder h_c),  own chain via XCD1 L2
//   XCD2..7 -> group_o (WcwT transpose + logits)
// FALLBACK (census != 32/XCD): blockIdx-based roles, sc1 everywhere (previous behavior).
struct SeqParams {
    const float* bih_v; const float* bhh_v;
    const float* bih_c; const float* bhh_c;
    const float* bout;  const int* y;
    const float* gi;    const float* Wc;  float* out;
    const unsigned short* WhhvB; const unsigned short* WhhcB; const unsigned short* WchhB;
    const unsigned short* WoutB; unsigned short* WcwTB;
    unsigned short* eo;    // 80 x (64x512) bf16  — remote (sc1) copy
    unsigned short* eoL;   // 80 x (64x512) bf16  — XCD0-local copy
    unsigned short* hv2B;  // 32 x (64x512) bf16  — remote (slot0 from enc_c)
    unsigned short* hv2L;  // 32 x (64x512) bf16  — XCD0-local copy (slots 1..31)
    float*          hv2F;  // 32 x (64x512) fp32  (decoder carry, read by group_c)
    unsigned short* hcdB;  // 31 x (64x512) bf16
    unsigned short* ecA;   // 80 x (64x512) bf16  — enc_c per-t h (write-once)
    unsigned short* zeroB;
    float* hcf; float* lossP; int* ctr;
};
// remote flags (stride 16 ints = 64B): F_EOr=0, F_ECr=512, F_HVr=1024, F_HCr=1536
// scalars: S_TR=+2048, S_LOG=+2064, S_LP=+2080
// local dense flags (4B stride): F_EOl=+2304(32), F_ECl=+2336(32), F_HVl=+2368(32)
// registration: R_XCNT=+2432(8), R_TOT=+2448
#define F_EOr (p.ctr)
#define F_ECr (p.ctr + 512)
#define F_HVr (p.ctr + 1024)
#define F_HCr (p.ctr + 1536)
#define S_TR  (p.ctr + 2048)
#define S_LOG (p.ctr + 2064)
#define S_LP  (p.ctr + 2080)
#define F_EOl (p.ctr + 2304)
#define F_ECl (p.ctr + 2336)
#define F_HVl (p.ctr + 2368)
#define R_XCNT (p.ctr + 2432)
#define R_TOT  (p.ctr + 2448)

// ================= group_v =================
template <bool L>
__device__ __forceinline__ void run_v(const SeqParams& p, int vid, unsigned short* Wlds) {
    const int lane = threadIdx.x & 63;
    const int wave = threadIdx.x >> 6;
    const int quad = lane >> 4, l15 = lane & 15;
    const f32x4 z4 = {0.f, 0.f, 0.f, 0.f};
    const int j0 = vid * 16;
    const int j = j0 + l15;
    const int m0 = wave * 16;
    const int b_ = m0 + quad * 4;
#pragma unroll
    for (int g = 0; g < 3; ++g)
        stage_swz(p.WhhvB + (size_t)(g * 512 + j0) * 512, Wlds + g * WTILE);
    __syncthreads();
    const float bhr = p.bhh_v[j], bhz = p.bhh_v[512 + j], bhn = p.bhh_v[1024 + j];
    float hp[4] = {0.f, 0.f, 0.f, 0.f};
    int fbv = 0;

    for (int t = 0; t < 80; ++t) {
        float gr[4], gz[4], gn[4];  // prefetch gi[t] (independent of flags)
        const float* gt = p.gi + (size_t)t * 98304;
#pragma unroll
        for (int r = 0; r < 4; ++r) {
            const float* gb = gt + (size_t)(b_ + r) * 1536;
            gr[r] = gb[j]; gz[r] = gb[512 + j]; gn[r] = gb[1024 + j];
        }
        f32x4 aR = z4, aZ = z4, aN = z4;
        if (t > 0) {
            if (L) {
                wait32<1>(F_EOl, F_EOr, t, fbv);
                mm3_p(p.eoL + (size_t)(t - 1) * 32768, m0, Wlds, lane, aR, aZ, aN);
            } else {
                flags_wait<1>(F_EOr, t);
                mm3_s(p.eo + (size_t)(t - 1) * 32768, m0, Wlds, lane, aR, aZ, aN);
            }
        }
        unsigned short hb[4];
#pragma unroll
        for (int r = 0; r < 4; ++r) {
            float rg = sigm(gr[r] + aR[r] + bhr);
            float zg = sigm(gz[r] + aZ[r] + bhz);
            float ng = tanh_f(gn[r] + rg * (aN[r] + bhn));
            float hn = (1.f - zg) * ng + zg * hp[r];
            hp[r] = hn;
            hb[r] = f2b(hn);
        }
        if (L) {   // local copy first: plain write-through stores, fast L2 publish
            unsigned short* el = p.eoL + (size_t)t * 32768;
#pragma unroll
            for (int r = 0; r < 4; ++r) el[(size_t)(b_ + r) * 512 + j] = hb[r];
            publish_l(F_EOl + vid, t + 1);
        }
        unsigned short* er = p.eo + (size_t)t * 32768;   // remote copy for group_c
#pragma unroll
        for (int r = 0; r < 4; ++r) stg_b16_sc(er + (size_t)(b_ + r) * 512 + j, hb[r]);
        block_publish(F_EOr + vid * 16, t + 1);
    }

    // ----- decoder h_v2 chain -----
    flags_wait<1>(F_ECr, 80);  // hcf + hv2B[0] ready
    const float bir = p.bih_v[j], biz = p.bih_v[512 + j], bin_ = p.bih_v[1024 + j];
    for (int s = 0; s <= 30; ++s) {
        if (s > 0) {
            if (L) wait32<1>(F_HVl, F_HVr, s, fbv);
            else   flags_wait<1>(F_HVr, s);
        }
        f32x4 aR = z4, aZ = z4, aN = z4;
        if (s == 0)      mm3_s(p.hv2B, m0, Wlds, lane, aR, aZ, aN);             // from enc_c (remote)
        else if (L)      mm3_p(p.hv2L + (size_t)s * 32768, m0, Wlds, lane, aR, aZ, aN);
        else             mm3_s(p.hv2B + (size_t)s * 32768, m0, Wlds, lane, aR, aZ, aN);
        float hn4[4];
#pragma unroll
        for (int r = 0; r < 4; ++r) {
            float hpv = (s == 0) ? ldg_f32_sc(p.hcf + (size_t)(b_ + r) * 512 + j) : hp[r];
            float rg = sigm(bir + aR[r] + bhr);
            float zg = sigm(biz + aZ[r] + bhz);
            float ng = tanh_f(bin_ + rg * (aN[r] + bhn));
            float hn = (1.f - zg) * ng + zg * hpv;
            hp[r] = hn;
            hn4[r] = hn;
        }
        if (L) {
            unsigned short* hl = p.hv2L + (size_t)(s + 1) * 32768;
#pragma unroll
            for (int r = 0; r < 4; ++r) hl[(size_t)(b_ + r) * 512 + j] = f2b(hn4[r]);
            publish_l(F_HVl + vid, s + 1);
        }
        unsigned short* hw = p.hv2B + (size_t)(s + 1) * 32768;
        float* hwF = p.hv2F + (size_t)(s + 1) * 32768;
#pragma unroll
        for (int r = 0; r < 4; ++r) {
            stg_b16_sc(hw + (size_t)(b_ + r) * 512 + j, f2b(hn4[r]));
            stg_b32_sc(hwF + (size_t)(b_ + r) * 512 + j, hn4[r]);
        }
        block_publish(F_HVr + vid * 16, s + 1);
    }

    // ----- loss (v-blocks 0..15: row b = vid*4+wave) -----
    if (vid < 16) {
        const int b = (vid << 2) | wave;
        scalar_wait<2>(S_LOG, 188);
        const float* lg = p.out + (size_t)b * 192000 + 186000;
        float m = -1e30f, sum = 0.f;
        for (int i = lane; i < 3000; i += 64) {
            union { unsigned long long u; float f[2]; } pr;
            pr.u = ldg_u64_sc(lg + 2 * i);
#pragma unroll
            for (int e = 0; e < 2; ++e) {
                float v = pr.f[e];
                float nm = fmaxf(m, v);
                sum = sum * __expf(m - nm) + __expf(v - nm);
                m = nm;
            }
        }
#pragma unroll
        for (int off = 32; off > 0; off >>= 1) {
            float m2 = __shfl_down(m, off);
            float s2 = __shfl_down(sum, off);
            float nm = fmaxf(m, m2);
            sum = sum * __expf(m - nm) + s2 * __expf(m2 - nm);
            m = nm;
        }
        if (lane == 0) {
            int yv = p.y[31 * 64 + b];
            float lgy = ldg_f32_sc(lg + yv);
            stg_b32_sc(p.lossP + b, (m + __logf(sum)) - lgy);
        }
        wave_add(S_LP);
        if (vid == 0 && wave == 0) {
            scalar_wait<1>(S_LP, 64);
            float v = ldg_f32_sc(p.lossP + lane);
#pragma unroll
            for (int off = 32; off > 0; off >>= 1) v += __shfl_down(v, off);
            if (lane == 0) p.out[12288000] = v * (1.f / 64.f);
        }
    }
}

// ================= group_c =================
template <bool L>
__device__ __forceinline__ void run_c(const SeqParams& p, int cid, unsigned short* Wlds) {
    const int lane = threadIdx.x & 63;
    const int wave = threadIdx.x >> 6;
    const int quad = lane >> 4, l15 = lane & 15;
    const f32x4 z4 = {0.f, 0.f, 0.f, 0.f};
    const int j0 = cid * 16;
    const int j = j0 + l15;
    const int m0 = wave * 16;
    const int b_ = m0 + quad * 4;
#pragma unroll
    for (int g = 0; g < 3; ++g) {
        stage_swz(p.WchhB + (size_t)(g * 512 + j0) * 512, Wlds + g * WTILE);
        stage_swz(p.WhhcB + (size_t)(g * 512 + j0) * 512, Wlds + (3 + g) * WTILE);
    }
    __syncthreads();
    const float bcr = p.bih_c[j] + p.bhh_c[j];
    const float bcz = p.bih_c[512 + j] + p.bhh_c[512 + j];
    const float bin_ = p.bih_c[1024 + j];
    const float bhn = p.bhh_c[1024 + j];
    float hp[4] = {0.f, 0.f, 0.f, 0.f};
    int fbc = 0;

    for (int t = 0; t < 80; ++t) {
        if (L) wait_rl<1>(F_EOr, t + 1, F_ECl, F_ECr, t, fbc);  // eo[t] remote; own chain local
        else   flags_wait2<1>(F_EOr, t + 1, F_ECr, t);
        const unsigned short* A1 = (t == 0) ? p.zeroB : p.ecA + (size_t)(t - 1) * 32768;
        f32x4 aR = z4, aZ = z4, aIN = z4, aHN = z4;
        if (L) mm6_rp(p.eo + (size_t)t * 32768, A1, m0, Wlds, lane, aR, aZ, aIN, aHN);
        else   mm6_s (p.eo + (size_t)t * 32768, A1, m0, Wlds, lane, aR, aZ, aIN, aHN);
        unsigned short hb[4]; float hn4[4];
#pragma unroll
        for (int r = 0; r < 4; ++r) {
            float rg = sigm(aR[r] + bcr);
            float zg = sigm(aZ[r] + bcz);
            float ng = tanh_f(aIN[r] + bin_ + rg * (aHN[r] + bhn));
            float hn = (1.f - zg) * ng + zg * hp[r];
            hp[r] = hn;
            hn4[r] = hn;
            hb[r] = f2b(hn);
        }
        unsigned short* ew = p.ecA + (size_t)t * 32768;
        if (L) {
#pragma unroll
            for (int r = 0; r < 4; ++r) ew[(size_t)(b_ + r) * 512 + j] = hb[r];
            publish_l(F_ECl + cid, t + 1);
            if (t == 79) {
#pragma unroll
                for (int r = 0; r < 4; ++r) {
                    stg_b16_sc(p.hv2B + (size_t)(b_ + r) * 512 + j, hb[r]);
                    stg_b32_sc(p.hcf + (size_t)(b_ + r) * 512 + j, hn4[r]);
                }
            }
            block_publish(F_ECr + cid * 16, t + 1);  // remote copy of flag (fallback + t=79 gate)
        } else {
#pragma unroll
            for (int r = 0; r < 4; ++r) {
                stg_b16_sc(ew + (size_t)(b_ + r) * 512 + j, hb[r]);
                if (t == 79) {
                    stg_b16_sc(p.hv2B + (size_t)(b_ + r) * 512 + j, hb[r]);
                    stg_b32_sc(p.hcf + (size_t)(b_ + r) * 512 + j, hn4[r]);
                }
            }
            block_publish(F_ECr + cid * 16, t + 1);
        }
    }

    // ----- decoder h_c (no inter-step chain) -----
    scalar_wait<4>(S_TR, 94);  // WcwT ready
    for (int s = 0; s <= 30; ++s) {
        float er[4], ez[4], en[4];   // prefetch embedding rows (y known in advance)
#pragma unroll
        for (int r = 0; r < 4; ++r) {
            const int yv = p.y[s * 64 + (b_ + r)];
            const unsigned short* em = p.WcwTB + (size_t)yv * 1536;
            er[r] = ldg_b16_sc(em + j);
            ez[r] = ldg_b16_sc(em + 512 + j);
            en[r] = ldg_b16_sc(em + 1024 + j);
        }
        flags_wait<1>(F_HVr, s + 1);
        const unsigned short* hv = p.hv2B + (size_t)(s + 1) * 32768;
        const float* hvF = p.hv2F + (size_t)(s + 1) * 32768;
        f32x4 aR = z4, aZ = z4, aIN = z4, aHN = z4;
        mm6_s(hv, hv, m0, Wlds, lane, aR, aZ, aIN, aHN);
        unsigned short* hc = p.hcdB + (size_t)s * 32768;
#pragma unroll
        for (int r = 0; r < 4; ++r) {
            float rg = sigm(aR[r] + er[r] + bcr);
            float zg = sigm(aZ[r] + ez[r] + bcz);
            float ng = tanh_f(aIN[r] + en[r] + bin_ + rg * (aHN[r] + bhn));
            float hpv = ldg_f32_sc(hvF + (size_t)(b_ + r) * 512 + j);
            stg_b16_sc(hc + (size_t)(b_ + r) * 512 + j, f2b((1.f - zg) * ng + zg * hpv));
        }
        block_publish(F_HCr + cid * 16, s + 1);
    }
}

// ================= group_o =================
__device__ __forceinline__ void run_o(const SeqParams& p, int oid, unsigned short* Wlds) {
    if (oid >= 188) return;           // 188 logits blocks x 32 cols cover 6000
    const int lane = threadIdx.x & 63;
    const int wave = threadIdx.x >> 6;
    const int quad = lane >> 4, l15 = lane & 15;
    const f32x4 z4 = {0.f, 0.f, 0.f, 0.f};
    const int w0 = oid * 32;
    const int ntl = (w0 + 32 <= 6000) ? 2 : 1;   // block 187: only 16 valid cols
    for (int tl = 0; tl < ntl; ++tl)
        stage_swz(p.WoutB + (size_t)(w0 + tl * 16) * 512, Wlds + tl * WTILE);
    __syncthreads();

    // --- WcwT transpose during encoder slack ---
    if (oid < 94) {
        float* tile = (float*)(Wlds + 16384);  // 64x65 fp32 scratch after 2 Wout tiles
        const int w0t = oid * 64;
        const int tx = threadIdx.x & 63, ty = threadIdx.x >> 6;
        for (int gt = 0; gt < 24; ++gt) {
            const int g0 = gt * 64;
            __syncthreads();
            for (int r = ty; r < 64; r += 4) {
                int w = w0t + tx;
                tile[r * 65 + tx] = (w < 6000) ? p.Wc[(size_t)(g0 + r) * 6512 + 512 + w] : 0.f;
            }
            __syncthreads();
            for (int r = ty; r < 64; r += 4) {
                int w = w0t + r;
                if (w < 6000)
                    stg_b16_sc(p.WcwTB + (size_t)w * 1536 + g0 + tx, f2b(tile[tx * 65 + r]));
            }
        }
        asm volatile("s_waitcnt vmcnt(0)" ::: "memory");
        __syncthreads();
        if (threadIdx.x == 0)
            __hip_atomic_fetch_add(S_TR, 1, __ATOMIC_RELAXED, __HIP_MEMORY_SCOPE_AGENT);
    }

    // --- logits ---
    const int m0 = wave * 16;
    const int b_ = m0 + quad * 4;
    float bo_[2];
#pragma unroll
    for (int tl = 0; tl < 2; ++tl) {
        int bi = w0 + tl * 16 + l15;
        bo_[tl] = p.bout[bi < 6000 ? bi : 5999];
    }
    for (int s = 0; s <= 30; ++s) {
        if (wave == 0) flags_wait<2>(F_HCr, s + 1);   // one wave polls; barrier releases rest
        __syncthreads();
        const unsigned short* ab =
            p.hcdB + (size_t)s * 32768 + (size_t)(m0 + l15) * 512 + quad * 8;
        s16x8 af[16];
#pragma unroll
        for (int c = 0; c < 16; ++c) af[c] = ldA_sc(ab + c * 32);
        for (int tl = 0; tl < ntl; ++tl) {
            f32x4 acc = z4;
#pragma unroll
            for (int c = 0; c < 16; ++c) acc = MFMA_B16(af[c], WF(Wlds, tl, c, lane), acc);
#pragma unroll
            for (int r = 0; r < 4; ++r)
                stg_b32_sc(p.out + (size_t)(b_ + r) * 192000 + (size_t)(s + 1) * 6000 +
                               w0 + tl * 16 + l15,
                           acc[r] + bo_[tl]);
        }
    }
    asm volatile("s_waitcnt vmcnt(0)" ::: "memory");
    __syncthreads();
    if (threadIdx.x == 0)
        __hip_atomic_fetch_add(S_LOG, 1, __ATOMIC_RELAXED, __HIP_MEMORY_SCOPE_AGENT);
}

__global__ __launch_bounds__(256, 1) void seq_kernel(SeqParams p) {
    __shared__ unsigned short Wlds[49152];  // 96 KiB -> 1 block/CU -> exactly 32 blocks/XCD
    __shared__ int s_role[3];
    if (threadIdx.x == 0) {
        int xcd;
        asm volatile("s_getreg_b32 %0, hwreg(HW_REG_XCC_ID)" : "=s"(xcd));
        xcd &= 7;
        int slot = __hip_atomic_fetch_add(R_XCNT + xcd, 1, __ATOMIC_RELAXED, __HIP_MEMORY_SCOPE_AGENT);
        __hip_atomic_fetch_add(R_TOT, 1, __ATOMIC_RELAXED, __HIP_MEMORY_SCOPE_AGENT);
        const int nb = (int)gridDim.x;
        while (__hip_atomic_load(R_TOT, __ATOMIC_RELAXED, __HIP_MEMORY_SCOPE_AGENT) < nb)
            __builtin_amdgcn_s_sleep(2);
        int ok = 1;
        for (int i = 0; i < 8; ++i)
            ok &= (__hip_atomic_load(R_XCNT + i, __ATOMIC_RELAXED, __HIP_MEMORY_SCOPE_AGENT) == 32);
        int role, idx;
        if (ok) {
            if (xcd == 0)      { role = 0; idx = slot; }
            else if (xcd == 1) { role = 1; idx = slot; }
            else               { role = 2; idx = slot + 32 * (xcd - 2); }
        } else {
            role = (blockIdx.x < 32) ? 0 : ((blockIdx.x < 64) ? 1 : 2);
            idx = (role == 0) ? (int)blockIdx.x
                              : ((role == 1) ? (int)blockIdx.x - 32 : (int)blockIdx.x - 64);
        }
        s_role[0] = role; s_role[1] = idx; s_role[2] = ok;
    }
    __syncthreads();
    const int role = s_role[0], idx = s_role[1], loc = s_role[2];
    if (role == 0) {
        if (loc) run_v<true>(p, idx, Wlds); else run_v<false>(p, idx, Wlds);
    } else if (role == 1) {
        if (loc) run_c<true>(p, idx, Wlds); else run_c<false>(p, idx, Wlds);
    } else {
        run_o(p, idx, Wlds);
    }
}

// ---------- host ----------
extern "C" void kernel_launch(void* const* d_in, const int* in_sizes, int n_in,
                              void* d_out, int out_size, void* d_ws, size_t ws_size,
                              hipStream_t stream) {
    const float* x     = (const float*)d_in[0];
    const int*   y     = (const int*)d_in[1];
    const float* Wih_v = (const float*)d_in[2];
    const float* Whh_v = (const float*)d_in[3];
    const float* bih_v = (const float*)d_in[4];
    const float* bhh_v = (const float*)d_in[5];
    const float* Wih_c = (const float*)d_in[6];
    const float* Whh_c = (const float*)d_in[7];
    const float* bih_c = (const float*)d_in[8];
    const float* bhh_c = (const float*)d_in[9];
    const float* Wout  = (const float*)d_in[10];
    const float* bout  = (const float*)d_in[11];
    float* out = (float*)d_out;

    char* w = (char*)d_ws;
    size_t o = 0;
    auto alloc = [&](size_t bytes) -> void* {
        void* p = (void*)(w + o);
        o += (bytes + 255) & ~(size_t)255;
        return p;
    };
    float*          gi    = (float*)alloc(7864320ull * 4);
    unsigned short* xB    = (unsigned short*)alloc(20971520ull * 2);
    unsigned short* WihB  = (unsigned short*)alloc(6291456ull * 2);
    unsigned short* WhhvB = (unsigned short*)alloc(786432ull * 2);
    unsigned short* WhhcB = (unsigned short*)alloc(786432ull * 2);
    unsigned short* WchhB = (unsigned short*)alloc(786432ull * 2);
    unsigned short* WoutB = (unsigned short*)alloc(3072000ull * 2);
    unsigned short* WcwTB = (unsigned short*)alloc(9216000ull * 2);
    unsigned short* eo    = (unsigned short*)alloc(80ull * 32768 * 2);
    unsigned short* eoL   = (unsigned short*)alloc(80ull * 32768 * 2);
    unsigned short* hv2B  = (unsigned short*)alloc(32ull * 32768 * 2);
    unsigned short* hv2L  = (unsigned short*)alloc(32ull * 32768 * 2);
    float*          hv2F  = (float*)alloc(32ull * 32768 * 4);
    unsigned short* hcdB  = (unsigned short*)alloc(31ull * 32768 * 2);
    unsigned short* ecA   = (unsigned short*)alloc(80ull * 32768 * 2);
    unsigned short* zeroB = (unsigned short*)alloc(32768ull * 2);
    float*          hcf   = (float*)alloc(32768ull * 4);
    float*          lossP = (float*)alloc(64ull * 4);
    int*            ctrs  = (int*)alloc(4096ull * 4);
    if (o > ws_size) return;

    prep_kernel<<<512, 256, 0, stream>>>(x, Wih_v, Whh_v, Whh_c, Wih_c, Wout, xB, WihB,
                                         WhhvB, WhhcB, WchhB, WoutB, zeroB, ctrs, out);
    gemm1_kernel<<<480, 256, 0, stream>>>(xB, WihB, bih_v, gi);

    SeqParams p;
    p.bih_v = bih_v; p.bhh_v = bhh_v; p.bih_c = bih_c; p.bhh_c = bhh_c;
    p.bout = bout; p.y = y; p.gi = gi; p.Wc = Wih_c; p.out = out;
    p.WhhvB = WhhvB; p.WhhcB = WhhcB; p.WchhB = WchhB; p.WoutB = WoutB; p.WcwTB = WcwTB;
    p.eo = eo; p.eoL = eoL; p.hv2B = hv2B; p.hv2L = hv2L; p.hv2F = hv2F; p.hcdB = hcdB;
    p.ecA = ecA; p.zeroB = zeroB;
    p.hcf = hcf; p.lossP = lossP; p.ctr = ctrs;
    void* args[] = {&p};
    hipLaunchCooperativeKernel((void*)seq_kernel, dim3(256), dim3(256), args, 0, stream);
}

// Round 2
// 1386.903 us; speedup vs baseline: 1.1343x; 1.1343x over previous
//
#include <hip/hip_runtime.h>

// ---------- types / helpers ----------
typedef short s16x8 __attribute__((ext_vector_type(8)));   // 8 bf16 (4 VGPRs) MFMA A/B frag
typedef float f32x4 __attribute__((ext_vector_type(4)));   // MFMA C/D frag
typedef unsigned short u16x4 __attribute__((ext_vector_type(4)));

#define MFMA_B16(a, b, c) __builtin_amdgcn_mfma_f32_16x16x32_bf16((a), (b), (c), 0, 0, 0)

__device__ __forceinline__ unsigned short f2b(float f) {   // fp32 -> bf16 RNE
    unsigned u = __builtin_bit_cast(unsigned, f);
    u = (u + 0x7fffu + ((u >> 16) & 1u)) >> 16;
    return (unsigned short)u;
}
__device__ __forceinline__ float b2f(unsigned short h) {
    unsigned u = ((unsigned)h) << 16;
    return __builtin_bit_cast(float, u);
}
__device__ __forceinline__ float sigm(float x) { return 1.f / (1.f + __expf(-x)); }
__device__ __forceinline__ float tanh_f(float x) {
    float t = __expf(-2.f * fabsf(x));
    float r = (1.f - t) / (1.f + t);
    return copysignf(r, x);
}

// ---------- coherent-bypass data ops (sc1; no cache-wide maintenance) ----------
__device__ __forceinline__ void stg_b16_sc(unsigned short* p, unsigned short v) {
    unsigned v32 = v;
    asm volatile("global_store_short %0, %1, off sc1" :: "v"(p), "v"(v32) : "memory");
}
__device__ __forceinline__ void stg_b32_sc(float* p, float v) {
    asm volatile("global_store_dword %0, %1, off sc1" :: "v"(p), "v"(v) : "memory");
}
__device__ __forceinline__ unsigned long long ldg_u64_sc(const void* p) {
    return __hip_atomic_load((unsigned long long*)p, __ATOMIC_RELAXED, __HIP_MEMORY_SCOPE_AGENT);
}
__device__ __forceinline__ float ldg_b16_sc(const unsigned short* p) {
    unsigned short v = __hip_atomic_load((unsigned short*)p, __ATOMIC_RELAXED, __HIP_MEMORY_SCOPE_AGENT);
    return b2f(v);
}
__device__ __forceinline__ float ldg_f32_sc(const float* p) {
    return __hip_atomic_load((float*)p, __ATOMIC_RELAXED, __HIP_MEMORY_SCOPE_AGENT);
}
__device__ __forceinline__ s16x8 ldA_sc(const unsigned short* p) {
    union { unsigned long long u[2]; s16x8 v; } r;
    r.u[0] = ldg_u64_sc(p);
    r.u[1] = ldg_u64_sc((const unsigned long long*)p + 1);
    return r.v;
}

// ---------- flag protocol: one 64B-separated dword flag per producer block ----------
__device__ __forceinline__ void block_publish(int* flag, int v) {
    asm volatile("s_waitcnt vmcnt(0)" ::: "memory");
    __syncthreads();
    if (threadIdx.x == 0)
        __hip_atomic_store(flag, v, __ATOMIC_RELAXED, __HIP_MEMORY_SCOPE_AGENT);
}
template <int SLP>
__device__ __forceinline__ void flags_wait2(const int* f1, int t1, const int* f2, int t2) {
    const int lane = threadIdx.x & 63;
    const int* ptr = (lane < 32) ? (f1 + lane * 16) : (f2 + (lane - 32) * 16);
    const int tgt = (lane < 32) ? t1 : t2;
    for (;;) {
        int v = __hip_atomic_load((int*)ptr, __ATOMIC_RELAXED, __HIP_MEMORY_SCOPE_AGENT);
        if (__all(v >= tgt)) break;
        __builtin_amdgcn_s_sleep(SLP);
    }
}
template <int SLP>
__device__ __forceinline__ void flags_wait(const int* f, int t) {
    flags_wait2<SLP>(f, t, f, t);
}
template <int SLP>
__device__ __forceinline__ void scalar_wait(int* c, int target) {
    while (__hip_atomic_load(c, __ATOMIC_RELAXED, __HIP_MEMORY_SCOPE_AGENT) < target)
        __builtin_amdgcn_s_sleep(SLP);
}
__device__ __forceinline__ void wave_add(int* c) {   // per-wave count (after drain)
    asm volatile("s_waitcnt vmcnt(0)" ::: "memory");
    if ((threadIdx.x & 63) == 0)
        __hip_atomic_fetch_add(c, 1, __ATOMIC_RELAXED, __HIP_MEMORY_SCOPE_AGENT);
}

// ---------- swizzled LDS weight tiles (16x512 bf16 in B-fragment order; conflict-free) ----------
#define WTILE 8192  // shorts per tile
#define WF(Wl, t, c, lane) (*(const s16x8*)((Wl) + (((t) * 16 + (c)) * 64 + (lane)) * 8))

__device__ __forceinline__ void stage_swz(const unsigned short* __restrict__ src,
                                          unsigned short* dst) {
    for (int idx = threadIdx.x; idx < 1024; idx += 256) {
        const int ln = idx & 63;
        *(uint4*)(dst + (size_t)idx * 8) =
            *(const uint4*)(src + (size_t)(ln & 15) * 512 + (ln >> 4) * 8 + ((idx >> 6)) * 32);
    }
}

// ---------- micro-GEMMs: A-frags via coherent loads, W from swizzled LDS ----------
__device__ __forceinline__ void mm3_s(const unsigned short* __restrict__ A, int m0,
                                      const unsigned short* Wl, int lane,
                                      f32x4& a0, f32x4& a1, f32x4& a2) {
    const unsigned short* ab = A + (size_t)(m0 + (lane & 15)) * 512 + (lane >> 4) * 8;
#pragma unroll
    for (int c = 0; c < 16; ++c) {
        s16x8 a = ldA_sc(ab + c * 32);
        a0 = MFMA_B16(a, WF(Wl, 0, c, lane), a0);
        a1 = MFMA_B16(a, WF(Wl, 1, c, lane), a1);
        a2 = MFMA_B16(a, WF(Wl, 2, c, lane), a2);
    }
}
__device__ __forceinline__ void mm6_s(const unsigned short* __restrict__ A0,
                                      const unsigned short* __restrict__ A1, int m0,
                                      const unsigned short* Wl, int lane,
                                      f32x4& aR, f32x4& aZ, f32x4& aIN, f32x4& aHN) {
    const unsigned short* a0 = A0 + (size_t)(m0 + (lane & 15)) * 512 + (lane >> 4) * 8;
    const unsigned short* a1 = A1 + (size_t)(m0 + (lane & 15)) * 512 + (lane >> 4) * 8;
#pragma unroll
    for (int c = 0; c < 16; ++c) {
        s16x8 x0 = ldA_sc(a0 + c * 32);
        s16x8 x1 = ldA_sc(a1 + c * 32);
        aR  = MFMA_B16(x0, WF(Wl, 0, c, lane), aR);
        aZ  = MFMA_B16(x0, WF(Wl, 1, c, lane), aZ);
        aIN = MFMA_B16(x0, WF(Wl, 2, c, lane), aIN);
        aR  = MFMA_B16(x1, WF(Wl, 3, c, lane), aR);
        aZ  = MFMA_B16(x1, WF(Wl, 4, c, lane), aZ);
        aHN = MFMA_B16(x1, WF(Wl, 5, c, lane), aHN);
    }
}

// ---------- prep ----------
__global__ void prep_kernel(const float* __restrict__ x, const float* __restrict__ Wih_v,
                            const float* __restrict__ Whh_v, const float* __restrict__ Whh_c,
                            const float* __restrict__ Wih_c, const float* __restrict__ Wout,
                            unsigned short* __restrict__ xB, unsigned short* __restrict__ WihB,
                            unsigned short* __restrict__ WhhvB, unsigned short* __restrict__ WhhcB,
                            unsigned short* __restrict__ WchhB, unsigned short* __restrict__ WoutB,
                            unsigned short* __restrict__ zeroB, int* __restrict__ ctrs,
                            float* __restrict__ out) {
    const int n = gridDim.x * blockDim.x;
    const int id0 = blockIdx.x * blockDim.x + threadIdx.x;
    for (int i = id0; i < 5242880; i += n) {   // x (b,t,f) fp32 -> xB (t*64+b, f) bf16
        const int e = i * 4;
        const int f = e & 4095, bt = e >> 12;  // bt = b*80+t
        const int b = bt / 80, t = bt - b * 80;
        float4 v = *(const float4*)(x + (size_t)e);
        u16x4 s = {f2b(v.x), f2b(v.y), f2b(v.z), f2b(v.w)};
        *(u16x4*)(xB + (size_t)(t * 64 + b) * 4096 + f) = s;
    }
    for (int i = id0; i < 1572864; i += n) {
        float4 v = *(const float4*)(Wih_v + (size_t)i * 4);
        u16x4 s = {f2b(v.x), f2b(v.y), f2b(v.z), f2b(v.w)};
        *(u16x4*)(WihB + (size_t)i * 4) = s;
    }
    for (int i = id0; i < 196608; i += n) {    // Whh_v / Whh_c / Wih_c[:, :512], vectorized
        const int e = i * 4;
        float4 a = *(const float4*)(Whh_v + e);
        u16x4 sa = {f2b(a.x), f2b(a.y), f2b(a.z), f2b(a.w)};
        *(u16x4*)(WhhvB + e) = sa;
        float4 b = *(const float4*)(Whh_c + e);
        u16x4 sb = {f2b(b.x), f2b(b.y), f2b(b.z), f2b(b.w)};
        *(u16x4*)(WhhcB + e) = sb;
        float4 d = *(const float4*)(Wih_c + (size_t)(e >> 9) * 6512 + (e & 511));
        u16x4 sd = {f2b(d.x), f2b(d.y), f2b(d.z), f2b(d.w)};
        *(u16x4*)(WchhB + e) = sd;
    }
    for (int i = id0; i < 768000; i += n) {    // Wout, vectorized
        float4 a = *(const float4*)(Wout + (size_t)i * 4);
        u16x4 s = {f2b(a.x), f2b(a.y), f2b(a.z), f2b(a.w)};
        *(u16x4*)(WoutB + (size_t)i * 4) = s;
    }
    for (int i = id0; i < 384000; i += n)      // probs[:,0,:] = 0 except probs[0,0,1]=1
        out[(size_t)(i / 6000) * 192000 + (i % 6000)] = (i == 1) ? 1.f : 0.f;
    for (int i = id0; i < 8192; i += n) ((unsigned long long*)zeroB)[i] = 0ull;
    for (int i = id0; i < 4096; i += n) ctrs[i] = 0;
}

// ---------- persistent pipeline kernel ----------
// blocks 0..31   group_v: enc_v chain + decoder h_v2 chain + loss
// blocks 32..63  group_c: enc_c chain + decoder h_c
// blocks 64..188 group_o: fused GEMM1 (t-major) + WcwT transpose + logits
struct SeqParams {
    const float* bih_v; const float* bhh_v;
    const float* bih_c; const float* bhh_c;
    const float* bout;  const int* y;
    float* gi;          const float* Wc;  float* out;
    const unsigned short* xB;    const unsigned short* WihB;
    const unsigned short* WhhvB; const unsigned short* WhhcB; const unsigned short* WchhB;
    const unsigned short* WoutB; unsigned short* WcwTB;
    unsigned short* eo;    // 80 x (64x512) bf16
    unsigned short* hv2B;  // 32 x (64x512) bf16
    float*          hv2F;  // 32 x (64x512) fp32 (decoder carry in fp32)
    unsigned short* hcdB;  // 31 x (64x512) bf16
    unsigned short* ecb0; unsigned short* ecb1; unsigned short* zeroB;
    float* hcf; float* lossP; int* ctr;
};
// flag arrays (stride 16 ints = 64B): F_EO=0, F_EC=512, F_HV=1024, F_HC=1536
// scalars: S_TR=+2048, S_LOG=+2064, S_LP=+2080; gemm per-t tile counters: S_GI=+2560(80)
#define F_EO (p.ctr)
#define F_EC (p.ctr + 512)
#define F_HV (p.ctr + 1024)
#define F_HC (p.ctr + 1536)
#define S_TR (p.ctr + 2048)
#define S_LOG (p.ctr + 2064)
#define S_LP (p.ctr + 2080)
#define S_GI (p.ctr + 2560)

__global__ __launch_bounds__(256, 1) void seq_kernel(SeqParams p) {
    __shared__ unsigned short Wlds[49152];  // 96 KiB
    const int blk = blockIdx.x;
    const int lane = threadIdx.x & 63;
    const int wave = threadIdx.x >> 6;
    const int quad = lane >> 4, l15 = lane & 15;
    const f32x4 z4 = {0.f, 0.f, 0.f, 0.f};

    if (blk < 32) {
        // ================= group_v =================
        const int j0 = blk * 16;
        const int j = j0 + l15;
        const int m0 = wave * 16;
        const int b_ = m0 + quad * 4;
#pragma unroll
        for (int g = 0; g < 3; ++g)
            stage_swz(p.WhhvB + (size_t)(g * 512 + j0) * 512, Wlds + g * WTILE);
        __syncthreads();
        const float bhr = p.bhh_v[j], bhz = p.bhh_v[512 + j], bhn = p.bhh_v[1024 + j];
        float hp[4] = {0.f, 0.f, 0.f, 0.f};
        int gall = 0;   // latched: all 960 gemm tiles done

        for (int t = 0; t < 80; ++t) {
            if (!gall) {   // gate on gi[t] availability (fused GEMM1 runs t-major, stays ahead)
                for (;;) {
                    int a = __hip_atomic_load(S_GI + t, __ATOMIC_RELAXED, __HIP_MEMORY_SCOPE_AGENT);
                    int z = __hip_atomic_load(S_GI + 79, __ATOMIC_RELAXED, __HIP_MEMORY_SCOPE_AGENT);
                    if (z >= 12) gall = 1;
                    if (a >= 12) break;
                    __builtin_amdgcn_s_sleep(2);
                }
            }
            float gr[4], gz[4], gn[4];  // prefetch gi[t] (LLC; overlaps with flag wait)
            const float* gt = p.gi + (size_t)t * 98304;
#pragma unroll
            for (int r = 0; r < 4; ++r) {
                const float* gb = gt + (size_t)(b_ + r) * 1536;
                gr[r] = ldg_f32_sc(gb + j);
                gz[r] = ldg_f32_sc(gb + 512 + j);
                gn[r] = ldg_f32_sc(gb + 1024 + j);
            }
            f32x4 aR = z4, aZ = z4, aN = z4;
            if (t > 0) {
                flags_wait<1>(F_EO, t);
                mm3_s(p.eo + (size_t)(t - 1) * 32768, m0, Wlds, lane, aR, aZ, aN);
            }
            unsigned short* eoW = p.eo + (size_t)t * 32768;
#pragma unroll
            for (int r = 0; r < 4; ++r) {
                float rg = sigm(gr[r] + aR[r] + bhr);
                float zg = sigm(gz[r] + aZ[r] + bhz);
                float ng = tanh_f(gn[r] + rg * (aN[r] + bhn));
                float hn = (1.f - zg) * ng + zg * hp[r];
                hp[r] = hn;
                stg_b16_sc(eoW + (size_t)(b_ + r) * 512 + j, f2b(hn));
            }
            block_publish(F_EO + blk * 16, t + 1);
        }

        // ----- decoder h_v2 chain -----
        flags_wait<1>(F_EC, 80);  // hcf + hv2B[0] ready
        const float bir = p.bih_v[j], biz = p.bih_v[512 + j], bin_ = p.bih_v[1024 + j];
        for (int s = 0; s <= 30; ++s) {
            if (s > 0) flags_wait<1>(F_HV, s);
            f32x4 aR = z4, aZ = z4, aN = z4;
            mm3_s(p.hv2B + (size_t)s * 32768, m0, Wlds, lane, aR, aZ, aN);
            unsigned short* hw = p.hv2B + (size_t)(s + 1) * 32768;
            float* hwF = p.hv2F + (size_t)(s + 1) * 32768;
#pragma unroll
            for (int r = 0; r < 4; ++r) {
                float hpv = (s == 0) ? ldg_f32_sc(p.hcf + (size_t)(b_ + r) * 512 + j) : hp[r];
                float rg = sigm(bir + aR[r] + bhr);
                float zg = sigm(biz + aZ[r] + bhz);
                float ng = tanh_f(bin_ + rg * (aN[r] + bhn));
                float hn = (1.f - zg) * ng + zg * hpv;
                hp[r] = hn;
                stg_b16_sc(hw + (size_t)(b_ + r) * 512 + j, f2b(hn));
                stg_b32_sc(hwF + (size_t)(b_ + r) * 512 + j, hn);
            }
            block_publish(F_HV + blk * 16, s + 1);
        }

        // ----- loss (blocks 0..15: row b = blk*4+wave) -----
        if (blk < 16) {
            const int b = (blk << 2) | wave;
            scalar_wait<2>(S_LOG, 125);
            const float* lg = p.out + (size_t)b * 192000 + 186000;
            float m = -1e30f, sum = 0.f;
            for (int i = lane; i < 3000; i += 64) {
                union { unsigned long long u; float f[2]; } pr;
                pr.u = ldg_u64_sc(lg + 2 * i);
#pragma unroll
                for (int e = 0; e < 2; ++e) {
                    float v = pr.f[e];
                    float nm = fmaxf(m, v);
                    sum = sum * __expf(m - nm) + __expf(v - nm);
                    m = nm;
                }
            }
#pragma unroll
            for (int off = 32; off > 0; off >>= 1) {
                float m2 = __shfl_down(m, off);
                float s2 = __shfl_down(sum, off);
                float nm = fmaxf(m, m2);
                sum = sum * __expf(m - nm) + s2 * __expf(m2 - nm);
                m = nm;
            }
            if (lane == 0) {
                int yv = p.y[31 * 64 + b];
                float lgy = ldg_f32_sc(lg + yv);
                stg_b32_sc(p.lossP + b, (m + __logf(sum)) - lgy);
            }
            wave_add(S_LP);
            if (blk == 0 && wave == 0) {
                scalar_wait<1>(S_LP, 64);
                float v = ldg_f32_sc(p.lossP + lane);
#pragma unroll
                for (int off = 32; off > 0; off >>= 1) v += __shfl_down(v, off);
                if (lane == 0) p.out[12288000] = v * (1.f / 64.f);
            }
        }
    } else if (blk < 64) {
        // ================= group_c =================
        const int cid = blk - 32;
        const int j0 = cid * 16;
        const int j = j0 + l15;
        const int m0 = wave * 16;
        const int b_ = m0 + quad * 4;
#pragma unroll
        for (int g = 0; g < 3; ++g) {
            stage_swz(p.WchhB + (size_t)(g * 512 + j0) * 512, Wlds + g * WTILE);
            stage_swz(p.WhhcB + (size_t)(g * 512 + j0) * 512, Wlds + (3 + g) * WTILE);
        }
        __syncthreads();
        const float bcr = p.bih_c[j] + p.bhh_c[j];
        const float bcz = p.bih_c[512 + j] + p.bhh_c[512 + j];
        const float bin_ = p.bih_c[1024 + j];
        const float bhn = p.bhh_c[1024 + j];
        float hp[4] = {0.f, 0.f, 0.f, 0.f};

        for (int t = 0; t < 80; ++t) {
            flags_wait2<1>(F_EO, t + 1, F_EC, t);  // eo[t] ready; own group at step t
            const unsigned short* A1 = (t == 0) ? p.zeroB : ((t & 1) ? p.ecb0 : p.ecb1);
            unsigned short* ew = (t & 1) ? p.ecb1 : p.ecb0;
            f32x4 aR = z4, aZ = z4, aIN = z4, aHN = z4;
            mm6_s(p.eo + (size_t)t * 32768, A1, m0, Wlds, lane, aR, aZ, aIN, aHN);
#pragma unroll
            for (int r = 0; r < 4; ++r) {
                float rg = sigm(aR[r] + bcr);
                float zg = sigm(aZ[r] + bcz);
                float ng = tanh_f(aIN[r] + bin_ + rg * (aHN[r] + bhn));
                float hn = (1.f - zg) * ng + zg * hp[r];
                hp[r] = hn;
                unsigned short hb = f2b(hn);
                stg_b16_sc(ew + (size_t)(b_ + r) * 512 + j, hb);
                if (t == 79) {
                    stg_b16_sc(p.hv2B + (size_t)(b_ + r) * 512 + j, hb);
                    stg_b32_sc(p.hcf + (size_t)(b_ + r) * 512 + j, hn);
                }
            }
            block_publish(F_EC + cid * 16, t + 1);
        }

        // ----- decoder h_c (no inter-step chain) -----
        scalar_wait<4>(S_TR, 94);  // WcwT ready
        for (int s = 0; s <= 30; ++s) {
            // prefetch embedding rows for this step (y known in advance)
            float er[4], ez[4], en[4];
#pragma unroll
            for (int r = 0; r < 4; ++r) {
                const int yv = p.y[s * 64 + (b_ + r)];
                const unsigned short* em = p.WcwTB + (size_t)yv * 1536;
                er[r] = ldg_b16_sc(em + j);
                ez[r] = ldg_b16_sc(em + 512 + j);
                en[r] = ldg_b16_sc(em + 1024 + j);
            }
            flags_wait<1>(F_HV, s + 1);
            const unsigned short* hv = p.hv2B + (size_t)(s + 1) * 32768;
            const float* hvF = p.hv2F + (size_t)(s + 1) * 32768;
            f32x4 aR = z4, aZ = z4, aIN = z4, aHN = z4;
            mm6_s(hv, hv, m0, Wlds, lane, aR, aZ, aIN, aHN);
            unsigned short* hc = p.hcdB + (size_t)s * 32768;
#pragma unroll
            for (int r = 0; r < 4; ++r) {
                float rg = sigm(aR[r] + er[r] + bcr);
                float zg = sigm(aZ[r] + ez[r] + bcz);
                float ng = tanh_f(aIN[r] + en[r] + bin_ + rg * (aHN[r] + bhn));
                float hpv = ldg_f32_sc(hvF + (size_t)(b_ + r) * 512 + j);
                stg_b16_sc(hc + (size_t)(b_ + r) * 512 + j, f2b((1.f - zg) * ng + zg * hpv));
            }
            block_publish(F_HC + cid * 16, s + 1);
        }
    } else {
        // ================= group_o =================
        const int bo = blk - 64;          // 0..124

        // --- fused GEMM1 (t-major): gi[t*64+b, g] = xB . WihB^T + bih_v ---
        // 960 tiles of 64 rows x 128 cols, K=4096; block bo takes q = bo, bo+120, ... (t = q/12)
        if (bo < 120) {
            unsigned short* As = Wlds;          // 64 x 72
            unsigned short* Bs = Wlds + 4608;   // 128 x 72
            const int tid = threadIdx.x;
            const int sra = tid >> 2, sca = (tid & 3) * 16;
            const int srb = tid >> 1, scb = (tid & 1) * 32;
            const int m0W = wave * 16;
            for (int q = bo; q < 960; q += 120) {
                const int t = q / 12, n0 = (q % 12) * 128;
                f32x4 acc[8];
#pragma unroll
                for (int jj = 0; jj < 8; ++jj) acc[jj] = z4;
                for (int k0 = 0; k0 < 4096; k0 += 64) {
                    __syncthreads();
                    const unsigned short* ax = p.xB + (size_t)(t * 64 + sra) * 4096 + k0 + sca;
                    *(s16x8*)&As[sra * 72 + sca]     = *(const s16x8*)(ax);
                    *(s16x8*)&As[sra * 72 + sca + 8] = *(const s16x8*)(ax + 8);
                    const unsigned short* bx = p.WihB + (size_t)(n0 + srb) * 4096 + k0 + scb;
                    *(s16x8*)&Bs[srb * 72 + scb]      = *(const s16x8*)(bx);
                    *(s16x8*)&Bs[srb * 72 + scb + 8]  = *(const s16x8*)(bx + 8);
                    *(s16x8*)&Bs[srb * 72 + scb + 16] = *(const s16x8*)(bx + 16);
                    *(s16x8*)&Bs[srb * 72 + scb + 24] = *(const s16x8*)(bx + 24);
                    __syncthreads();
#pragma unroll
                    for (int kk = 0; kk < 2; ++kk) {
                        s16x8 af = *(const s16x8*)&As[(m0W + l15) * 72 + kk * 32 + quad * 8];
#pragma unroll
                        for (int jj = 0; jj < 8; ++jj)
                            acc[jj] = MFMA_B16(
                                af, *(const s16x8*)&Bs[(jj * 16 + l15) * 72 + kk * 32 + quad * 8],
                                acc[jj]);
                    }
                }
#pragma unroll
                for (int jj = 0; jj < 8; ++jj)
#pragma unroll
                    for (int r = 0; r < 4; ++r) {
                        const int col = n0 + jj * 16 + l15;
                        const int row = t * 64 + m0W + quad * 4 + r;
                        stg_b32_sc(p.gi + (size_t)row * 1536 + col, acc[jj][r] + p.bih_v[col]);
                    }
                asm volatile("s_waitcnt vmcnt(0)" ::: "memory");
                __syncthreads();
                if (threadIdx.x == 0)
                    __hip_atomic_fetch_add(S_GI + t, 1, __ATOMIC_RELAXED, __HIP_MEMORY_SCOPE_AGENT);
            }
            __syncthreads();
        }

        // --- stage Wout tiles (48 cols each) ---
        const int w0 = bo * 48;
#pragma unroll
        for (int tl = 0; tl < 3; ++tl)
            stage_swz(p.WoutB + (size_t)(w0 + tl * 16) * 512, Wlds + tl * WTILE);
        __syncthreads();

        // --- WcwT transpose during encoder slack: block bo handles cols bo*64..+63 ---
        if (bo < 94) {
            float* tile = (float*)(Wlds + 24576);  // 64x65 fp32 scratch after Wout tiles
            const int w0t = bo * 64;
            const int tx = threadIdx.x & 63, ty = threadIdx.x >> 6;
            for (int gt = 0; gt < 24; ++gt) {
                const int g0 = gt * 64;
                __syncthreads();
                for (int r = ty; r < 64; r += 4) {
                    int w = w0t + tx;
                    tile[r * 65 + tx] = (w < 6000) ? p.Wc[(size_t)(g0 + r) * 6512 + 512 + w] : 0.f;
                }
                __syncthreads();
                for (int r = ty; r < 64; r += 4) {
                    int w = w0t + r;
                    if (w < 6000)
                        stg_b16_sc(p.WcwTB + (size_t)w * 1536 + g0 + tx, f2b(tile[tx * 65 + r]));
                }
            }
            asm volatile("s_waitcnt vmcnt(0)" ::: "memory");
            __syncthreads();
            if (threadIdx.x == 0)
                __hip_atomic_fetch_add(S_TR, 1, __ATOMIC_RELAXED, __HIP_MEMORY_SCOPE_AGENT);
        }

        // --- logits ---
        const int m0 = wave * 16;
        const int b_ = m0 + quad * 4;
        float bo_[3];
#pragma unroll
        for (int tl = 0; tl < 3; ++tl) bo_[tl] = p.bout[w0 + tl * 16 + l15];

        for (int s = 0; s <= 30; ++s) {
            if (wave == 0) {   // one wave polls (4x less LLC poll traffic); barrier releases rest
                if (s == 0) flags_wait<16>(F_HC, 1);
                else        flags_wait<2>(F_HC, s + 1);
            }
            __syncthreads();
            const unsigned short* ab =
                p.hcdB + (size_t)s * 32768 + (size_t)(m0 + l15) * 512 + quad * 8;
            s16x8 af[16];
#pragma unroll
            for (int c = 0; c < 16; ++c) af[c] = ldA_sc(ab + c * 32);
#pragma unroll
            for (int tl = 0; tl < 3; ++tl) {
                f32x4 acc = z4;
#pragma unroll
                for (int c = 0; c < 16; ++c) acc = MFMA_B16(af[c], WF(Wlds, tl, c, lane), acc);
#pragma unroll
                for (int r = 0; r < 4; ++r)
                    stg_b32_sc(p.out + (size_t)(b_ + r) * 192000 + (size_t)(s + 1) * 6000 +
                                   w0 + tl * 16 + l15,
                               acc[r] + bo_[tl]);
            }
        }
        asm volatile("s_waitcnt vmcnt(0)" ::: "memory");
        __syncthreads();
        if (threadIdx.x == 0)
            __hip_atomic_fetch_add(S_LOG, 1, __ATOMIC_RELAXED, __HIP_MEMORY_SCOPE_AGENT);
    }
}

// ---------- host ----------
extern "C" void kernel_launch(void* const* d_in, const int* in_sizes, int n_in,
                              void* d_out, int out_size, void* d_ws, size_t ws_size,
                              hipStream_t stream) {
    const float* x     = (const float*)d_in[0];
    const int*   y     = (const int*)d_in[1];
    const float* Wih_v = (const float*)d_in[2];
    const float* Whh_v = (const float*)d_in[3];
    const float* bih_v = (const float*)d_in[4];
    const float* bhh_v = (const float*)d_in[5];
    const float* Wih_c = (const float*)d_in[6];
    const float* Whh_c = (const float*)d_in[7];
    const float* bih_c = (const float*)d_in[8];
    const float* bhh_c = (const float*)d_in[9];
    const float* Wout  = (const float*)d_in[10];
    const float* bout  = (const float*)d_in[11];
    float* out = (float*)d_out;

    char* w = (char*)d_ws;
    size_t o = 0;
    auto alloc = [&](size_t bytes) -> void* {
        void* p = (void*)(w + o);
        o += (bytes + 255) & ~(size_t)255;
        return p;
    };
    float*          gi    = (float*)alloc(7864320ull * 4);
    unsigned short* xB    = (unsigned short*)alloc(20971520ull * 2);
    unsigned short* WihB  = (unsigned short*)alloc(6291456ull * 2);
    unsigned short* WhhvB = (unsigned short*)alloc(786432ull * 2);
    unsigned short* WhhcB = (unsigned short*)alloc(786432ull * 2);
    unsigned short* WchhB = (unsigned short*)alloc(786432ull * 2);
    unsigned short* WoutB = (unsigned short*)alloc(3072000ull * 2);
    unsigned short* WcwTB = (unsigned short*)alloc(9216000ull * 2);
    unsigned short* eo    = (unsigned short*)alloc(80ull * 32768 * 2);
    unsigned short* hv2B  = (unsigned short*)alloc(32ull * 32768 * 2);
    float*          hv2F  = (float*)alloc(32ull * 32768 * 4);
    unsigned short* hcdB  = (unsigned short*)alloc(31ull * 32768 * 2);
    unsigned short* ecb0  = (unsigned short*)alloc(32768ull * 2);
    unsigned short* ecb1  = (unsigned short*)alloc(32768ull * 2);
    unsigned short* zeroB = (unsigned short*)alloc(32768ull * 2);
    float*          hcf   = (float*)alloc(32768ull * 4);
    float*          lossP = (float*)alloc(64ull * 4);
    int*            ctrs  = (int*)alloc(4096ull * 4);
    if (o > ws_size) return;

    prep_kernel<<<512, 256, 0, stream>>>(x, Wih_v, Whh_v, Whh_c, Wih_c, Wout, xB, WihB,
                                         WhhvB, WhhcB, WchhB, WoutB, zeroB, ctrs, out);

    SeqParams p;
    p.bih_v = bih_v; p.bhh_v = bhh_v; p.bih_c = bih_c; p.bhh_c = bhh_c;
    p.bout = bout; p.y = y; p.gi = gi; p.Wc = Wih_c; p.out = out;
    p.xB = xB; p.WihB = WihB;
    p.WhhvB = WhhvB; p.WhhcB = WhhcB; p.WchhB = WchhB; p.WoutB = WoutB; p.WcwTB = WcwTB;
    p.eo = eo; p.hv2B = hv2B; p.hv2F = hv2F; p.hcdB = hcdB;
    p.ecb0 = ecb0; p.ecb1 = ecb1; p.zeroB = zeroB;
    p.hcf = hcf; p.lossP = lossP; p.ctr = ctrs;
    void* args[] = {&p};
    hipLaunchCooperativeKernel((void*)seq_kernel, dim3(189), dim3(256), args, 0, stream);
}